// Round 9
// baseline (4717.865 us; speedup 1.0000x reference)
//
#include <hip/hip_runtime.h>

#define N_NODES 100000
#define BATCH   256
#define NUM_TAU 4
#define ORDER   8
#define NB      ((size_t)N_NODES * BATCH)   // 25,600,000 elements per tau slice
#define NBUK    98                          // buckets of 1024 nodes (id>>10)
#define NBLK    391                         // ceil(N_NODES/256) for scans
#define SLICES  16
#define SCOLS   16                          // cols per slice (16 x 16 = 256)
#define NB_SL   ((size_t)N_NODES * SCOLS)   // elems per slice (3.2 MB bf16)
#define CHUNKS2 1563                        // ceil(100000 / 64) rows per block = 64

__device__ __forceinline__ unsigned short f2bf(float f) {
    unsigned int u = __float_as_uint(f);
    u += 0x7FFFu + ((u >> 16) & 1u);   // round-to-nearest-even
    return (unsigned short)(u >> 16);
}
__device__ __forceinline__ float bf2f(unsigned short h) {
    return __uint_as_float((unsigned int)h << 16);
}

// ---------------- CSR build (R6 proven): hist + scan + LDS bucketize + place ----------------

__global__ void hist_kernel(const int* __restrict__ dst, int* __restrict__ counts, int E) {
    int e = blockIdx.x * blockDim.x + threadIdx.x;
    if (e < E) atomicAdd(&counts[dst[e]], 1);
}

__global__ void scan1(const int* __restrict__ counts, int* __restrict__ blockSum) {
    __shared__ int s[256];
    int n = blockIdx.x * 256 + threadIdx.x;
    s[threadIdx.x] = (n < N_NODES) ? counts[n] : 0;
    __syncthreads();
    for (int st = 128; st > 0; st >>= 1) {
        if (threadIdx.x < st) s[threadIdx.x] += s[threadIdx.x + st];
        __syncthreads();
    }
    if (threadIdx.x == 0) blockSum[blockIdx.x] = s[0];
}

__global__ void scan2(int* __restrict__ blockSum) {   // exclusive scan of NBLK values
    __shared__ int s[512];
    int t = threadIdx.x;
    int v = (t < NBLK) ? blockSum[t] : 0;
    s[t] = v;
    __syncthreads();
    for (int st = 1; st < 512; st <<= 1) {
        int u = (t >= st) ? s[t - st] : 0;
        __syncthreads();
        s[t] += u;
        __syncthreads();
    }
    if (t < NBLK) blockSum[t] = s[t] - v;
}

__global__ void scan3(const int* __restrict__ counts, const int* __restrict__ blockSumEx,
                      int* __restrict__ rowStart) {
    __shared__ int s[256];
    int n = blockIdx.x * 256 + threadIdx.x;
    int v = (n < N_NODES) ? counts[n] : 0;
    s[threadIdx.x] = v;
    __syncthreads();
    for (int st = 1; st < 256; st <<= 1) {
        int u = (threadIdx.x >= st) ? s[threadIdx.x - st] : 0;
        __syncthreads();
        s[threadIdx.x] += u;
        __syncthreads();
    }
    if (n < N_NODES) rowStart[n] = blockSumEx[blockIdx.x] + s[threadIdx.x] - v;
}

__global__ void initcur_kernel(const int* __restrict__ rowStart, int* __restrict__ cursor,
                               int* __restrict__ bcur) {
    int n = blockIdx.x * 256 + threadIdx.x;
    if (n < N_NODES) cursor[n] = rowStart[n];
    if (n < NBUK) bcur[n] = rowStart[n << 10];
}

#define EPT 16
__global__ void bucketize_kernel(const int* __restrict__ src, const int* __restrict__ dst,
                                 const float* __restrict__ w, int* __restrict__ bcur,
                                 int2* __restrict__ isw, int* __restrict__ idn, int E) {
    __shared__ int cnt[NBUK], base[NBUK], off[NBUK];
    int e0 = blockIdx.x * (256 * EPT);
    for (int i = threadIdx.x; i < NBUK; i += 256) { cnt[i] = 0; off[i] = 0; }
    __syncthreads();
    #pragma unroll
    for (int i = 0; i < EPT; ++i) {
        int e = e0 + i * 256 + threadIdx.x;
        if (e < E) atomicAdd(&cnt[dst[e] >> 10], 1);
    }
    __syncthreads();
    for (int i = threadIdx.x; i < NBUK; i += 256) {
        int c = cnt[i];
        base[i] = c ? atomicAdd(&bcur[i], c) : 0;
    }
    __syncthreads();
    #pragma unroll
    for (int i = 0; i < EPT; ++i) {
        int e = e0 + i * 256 + threadIdx.x;
        if (e < E) {
            int d = dst[e];
            int b = d >> 10;
            int p = base[b] + atomicAdd(&off[b], 1);
            isw[p] = make_int2(src[e], __float_as_int(w[e]));
            idn[p] = d;
        }
    }
}

__global__ void place_kernel(const int2* __restrict__ isw, const int* __restrict__ idn,
                             int* __restrict__ cursor, int2* __restrict__ csr_pair, int E) {
    int e = blockIdx.x * blockDim.x + threadIdx.x;
    if (e < E) {
        int d = idn[e];
        int p = atomicAdd(&cursor[d], 1);
        csr_pair[p] = isw[e];
    }
}

// ---------------- sparse m1 = A @ onehot  (m1 fp32, lives in out slice 0) ----------------

__global__ void colmap_kernel(const int* __restrict__ bi, int* __restrict__ col_of_node,
                              int* __restrict__ next_dup) {
    int j = threadIdx.x;  // 256
    int prev = atomicExch(&col_of_node[bi[j]], j);
    next_dup[j] = prev;
}

__global__ void m1_edges_kernel(const int* __restrict__ src, const int* __restrict__ dst,
                                const float* __restrict__ w,
                                const int* __restrict__ col_of_node,
                                const int* __restrict__ next_dup,
                                float* __restrict__ m1, int* __restrict__ flag, int E) {
    int e = blockIdx.x * blockDim.x + threadIdx.x;
    if (e >= E) return;
    int j = col_of_node[src[e]];
    if (j < 0) return;
    float we = w[e];
    int d = dst[e];
    flag[d] = 1;
    size_t rb = (size_t)d * BATCH;
    while (j >= 0) {
        atomicAdd(&m1[rb + j], we);
        j = next_dup[j];
    }
}

// ---------------- k=2: fp32 m1 (sparse rows, flag-skipped) -> bf16 m2 (slice-major) ----------------
__global__ void spmm_k2(const float* __restrict__ m1, unsigned short* __restrict__ m2,
                        const int* __restrict__ rowStart, const int* __restrict__ counts,
                        const int2* __restrict__ csr_pair, const int* __restrict__ flag) {
    int wave = threadIdx.x >> 6;
    int lane = threadIdx.x & 63;
    int node = blockIdx.x * 4 + wave;
    if (node >= N_NODES) return;
    int col0 = lane * 4;

    int start = rowStart[node];
    int len   = counts[node];

    float4 acc = make_float4(0.f, 0.f, 0.f, 0.f);
    for (int i = 0; i < len; ++i) {
        int2 pr = csr_pair[start + i];
        if (flag[pr.x]) {
            float w = __int_as_float(pr.y);
            float4 v = *(const float4*)(m1 + (size_t)pr.x * BATCH + col0);
            acc.x += w * v.x; acc.y += w * v.y; acc.z += w * v.z; acc.w += w * v.w;
        }
    }
    ushort4 o;
    o.x = f2bf(acc.x); o.y = f2bf(acc.y); o.z = f2bf(acc.z); o.w = f2bf(acc.w);
    int slice = col0 >> 4;
    int off   = col0 & 15;
    *(ushort4*)(m2 + (size_t)slice * NB_SL + (size_t)node * SCOLS + off) = o;
}

// ---------------- sliced bf16 SpMM v2: group-per-row, nt csr, 32-bit addressing ----------------
// Wave = 16 groups x 4 lanes. Group g owns row (rowBase+g); lane c owns cols 4c..4c+3.
// Slice input = 3.2 MB -> per-XCD-L2 resident; csr read non-temporally to avoid thrash.
__global__ void spmm_bf_slice2(const unsigned short* __restrict__ min_,
                               unsigned short* __restrict__ mout,
                               const int* __restrict__ rowStart, const int* __restrict__ counts,
                               const long long* __restrict__ csr_ll) {
    int slice = blockIdx.x / CHUNKS2;
    int chunk = blockIdx.x - slice * CHUNKS2;
    int wave = threadIdx.x >> 6;
    int lane = threadIdx.x & 63;
    int g = lane >> 2;         // group 0..15 -> row
    int c = lane & 3;          // col quad 0..3

    int node = (chunk * 4 + wave) * 16 + g;
    if (node >= N_NODES) return;

    const unsigned short* msl = min_ + (size_t)slice * NB_SL;
    unsigned short*       osl = mout + (size_t)slice * NB_SL;

    int start = rowStart[node];
    int len   = counts[node];
    int coff  = c * 4;  // ushort offset within 16-col row

    float a0 = 0.f, a1 = 0.f, a2 = 0.f, a3 = 0.f;
    int i = 0;
    for (; i + 4 <= len; i += 4) {
        long long p0 = __builtin_nontemporal_load(csr_ll + start + i + 0);
        long long p1 = __builtin_nontemporal_load(csr_ll + start + i + 1);
        long long p2 = __builtin_nontemporal_load(csr_ll + start + i + 2);
        long long p3 = __builtin_nontemporal_load(csr_ll + start + i + 3);
        uint2 v0 = *(const uint2*)(msl + ((int)p0 * SCOLS + coff));
        uint2 v1 = *(const uint2*)(msl + ((int)p1 * SCOLS + coff));
        uint2 v2 = *(const uint2*)(msl + ((int)p2 * SCOLS + coff));
        uint2 v3 = *(const uint2*)(msl + ((int)p3 * SCOLS + coff));
        float w0 = __int_as_float((int)(p0 >> 32));
        float w1 = __int_as_float((int)(p1 >> 32));
        float w2 = __int_as_float((int)(p2 >> 32));
        float w3 = __int_as_float((int)(p3 >> 32));
        a0 += w0 * __uint_as_float(v0.x << 16);
        a1 += w0 * __uint_as_float(v0.x & 0xFFFF0000u);
        a2 += w0 * __uint_as_float(v0.y << 16);
        a3 += w0 * __uint_as_float(v0.y & 0xFFFF0000u);
        a0 += w1 * __uint_as_float(v1.x << 16);
        a1 += w1 * __uint_as_float(v1.x & 0xFFFF0000u);
        a2 += w1 * __uint_as_float(v1.y << 16);
        a3 += w1 * __uint_as_float(v1.y & 0xFFFF0000u);
        a0 += w2 * __uint_as_float(v2.x << 16);
        a1 += w2 * __uint_as_float(v2.x & 0xFFFF0000u);
        a2 += w2 * __uint_as_float(v2.y << 16);
        a3 += w2 * __uint_as_float(v2.y & 0xFFFF0000u);
        a0 += w3 * __uint_as_float(v3.x << 16);
        a1 += w3 * __uint_as_float(v3.x & 0xFFFF0000u);
        a2 += w3 * __uint_as_float(v3.y << 16);
        a3 += w3 * __uint_as_float(v3.y & 0xFFFF0000u);
    }
    for (; i < len; ++i) {
        long long p = __builtin_nontemporal_load(csr_ll + start + i);
        uint2 v = *(const uint2*)(msl + ((int)p * SCOLS + coff));
        float w = __int_as_float((int)(p >> 32));
        a0 += w * __uint_as_float(v.x << 16);
        a1 += w * __uint_as_float(v.x & 0xFFFF0000u);
        a2 += w * __uint_as_float(v.y << 16);
        a3 += w * __uint_as_float(v.y & 0xFFFF0000u);
    }

    uint2 o;
    o.x = ((unsigned int)f2bf(a1) << 16) | (unsigned int)f2bf(a0);
    o.y = ((unsigned int)f2bf(a3) << 16) | (unsigned int)f2bf(a2);
    *(uint2*)(osl + ((size_t)node * SCOLS + coff)) = o;
}

// ---------------- combine: out[t] = c[t,0]*onehot + c[t,1]*m1 + sum_{k>=2} c[t,k]*m_k ----------------
// m1 fp32 row-major in out slice 0 (in-place); m2..m8 bf16 slice-major in ws.
__global__ void combine_bf(float* __restrict__ out, const unsigned short* __restrict__ m28,
                           const float* __restrict__ coeffs, const int* __restrict__ bi) {
    size_t tid = (size_t)blockIdx.x * blockDim.x + threadIdx.x;
    size_t base = tid * 4;
    if (base >= NB) return;
    int node = (int)(base >> 8);
    int j0   = (int)(base & 255);
    int slice = j0 >> 4;
    int off   = j0 & 15;
    size_t sbase = (size_t)slice * NB_SL + (size_t)node * SCOLS + off;

    float4 p[ORDER];
    p[0] = *(const float4*)(out + base);  // m1 (slice 0, in-place)
    #pragma unroll
    for (int k = 2; k <= ORDER; ++k) {
        ushort4 v = *(const ushort4*)(m28 + (size_t)(k - 2) * NB + sbase);
        p[k - 1] = make_float4(bf2f(v.x), bf2f(v.y), bf2f(v.z), bf2f(v.w));
    }

    float oh[4];
    #pragma unroll
    for (int i = 0; i < 4; ++i) oh[i] = (bi[j0 + i] == node) ? 1.0f : 0.0f;

    #pragma unroll
    for (int t = 0; t < NUM_TAU; ++t) {
        float c0 = coeffs[t * (ORDER + 1)];
        float4 o = make_float4(c0 * oh[0], c0 * oh[1], c0 * oh[2], c0 * oh[3]);
        #pragma unroll
        for (int k = 1; k <= ORDER; ++k) {
            float c = coeffs[t * (ORDER + 1) + k];
            o.x += c * p[k - 1].x;
            o.y += c * p[k - 1].y;
            o.z += c * p[k - 1].z;
            o.w += c * p[k - 1].w;
        }
        *(float4*)(out + (size_t)t * NB + base) = o;
    }
}

// ---------------- fallback scheme B (fp32 path, row-major) ----------------

__global__ void spmm_half(const float* __restrict__ min_, float* __restrict__ mout,
                          const int* __restrict__ rowStart, const int* __restrict__ counts,
                          const int2* __restrict__ csr_pair, int colOff) {
    int wave = threadIdx.x >> 6;
    int lane = threadIdx.x & 63;
    int node = blockIdx.x * 4 + wave;
    if (node >= N_NODES) return;
    int c = colOff + lane * 2;
    int start = rowStart[node];
    int len   = counts[node];
    float2 acc = make_float2(0.f, 0.f);
    int i = 0;
    for (; i + 8 <= len; i += 8) {
        int2 pr[8];
        #pragma unroll
        for (int u = 0; u < 8; ++u) pr[u] = csr_pair[start + i + u];
        float2 v[8];
        #pragma unroll
        for (int u = 0; u < 8; ++u)
            v[u] = *(const float2*)(min_ + (size_t)pr[u].x * BATCH + c);
        #pragma unroll
        for (int u = 0; u < 8; ++u) {
            float w = __int_as_float(pr[u].y);
            acc.x += w * v[u].x;
            acc.y += w * v[u].y;
        }
    }
    for (; i < len; ++i) {
        int2 pr = csr_pair[start + i];
        float w = __int_as_float(pr.y);
        float2 v = *(const float2*)(min_ + (size_t)pr.x * BATCH + c);
        acc.x += w * v.x;
        acc.y += w * v.y;
    }
    *(float2*)(mout + (size_t)node * BATCH + c) = acc;
}

__global__ void combine_kernel(float* __restrict__ out, const float* __restrict__ m14,
                               const float* __restrict__ coeffs, const int* __restrict__ bi) {
    size_t tid = (size_t)blockIdx.x * blockDim.x + threadIdx.x;
    size_t base = tid * 4;
    if (base >= NB) return;
    int node = (int)(base >> 8);
    int j0   = (int)(base & 255);
    float4 p[ORDER];
    #pragma unroll
    for (int k = 1; k <= 4; ++k)
        p[k - 1] = *(const float4*)(m14 + (size_t)(k - 1) * NB + base);
    #pragma unroll
    for (int k = 5; k <= 8; ++k)
        p[k - 1] = *(const float4*)(out + (size_t)(k - 5) * NB + base);
    float oh[4];
    #pragma unroll
    for (int i = 0; i < 4; ++i) oh[i] = (bi[j0 + i] == node) ? 1.0f : 0.0f;
    #pragma unroll
    for (int t = 0; t < NUM_TAU; ++t) {
        float c0 = coeffs[t * (ORDER + 1)];
        float4 o = make_float4(c0 * oh[0], c0 * oh[1], c0 * oh[2], c0 * oh[3]);
        #pragma unroll
        for (int k = 1; k <= ORDER; ++k) {
            float c = coeffs[t * (ORDER + 1) + k];
            o.x += c * p[k - 1].x;
            o.y += c * p[k - 1].y;
            o.z += c * p[k - 1].z;
            o.w += c * p[k - 1].w;
        }
        *(float4*)(out + (size_t)t * NB + base) = o;
    }
}

extern "C" void kernel_launch(void* const* d_in, const int* in_sizes, int n_in,
                              void* d_out, int out_size, void* d_ws, size_t ws_size,
                              hipStream_t stream) {
    const float* coeffs = (const float*)d_in[0];
    const float* ew     = (const float*)d_in[1];
    const int*   src    = (const int*)d_in[2];
    const int*   dst    = (const int*)d_in[3];
    const int*   bi     = (const int*)d_in[4];   // int32 on device (JAX x64 disabled)
    const int E = in_sizes[1];

    float* out = (float*)d_out;

    auto align_up = [](uintptr_t v, uintptr_t a) { return (v + a - 1) & ~(a - 1); };

    uintptr_t p0 = (uintptr_t)d_ws;
    int* counts      = (int*)p0;  p0 += (size_t)N_NODES * 4;  p0 = align_up(p0, 256);
    int* rowStart    = (int*)p0;  p0 += (size_t)N_NODES * 4;  p0 = align_up(p0, 256);
    int* cursor      = (int*)p0;  p0 += (size_t)N_NODES * 4;  p0 = align_up(p0, 256);
    int* blockSum    = (int*)p0;  p0 += (size_t)NBLK * 4;     p0 = align_up(p0, 256);
    int* bcur        = (int*)p0;  p0 += (size_t)NBUK * 4;     p0 = align_up(p0, 256);
    int* col_of_node = (int*)p0;  p0 += (size_t)N_NODES * 4;  p0 = align_up(p0, 256);
    int* next_dup    = (int*)p0;  p0 += 1024;                 p0 = align_up(p0, 256);
    int* flag        = (int*)p0;  p0 += (size_t)N_NODES * 4;  p0 = align_up(p0, 256);
    int2* csr_pair   = (int2*)p0; p0 += (size_t)E * 8;        p0 = align_up(p0, 256);
    void* big        = (void*)p0;
    size_t big_bytes = ((uintptr_t)d_ws + ws_size > p0) ? ((uintptr_t)d_ws + ws_size - p0) : 0;

    int eb = (E + 255) / 256;
    int nodeGrid = (N_NODES + 3) / 4;
    int cgrid = (int)((NB / 4 + 255) / 256);

    // intermediate bucket-ordered edge buffer overlaps the tail of `big`
    // (that region is only written by the late spmm steps, long after place_kernel).
    bool schemeA = (big_bytes >= 7 * NB * 2);
    uintptr_t ibase;
    if (schemeA) ibase = (uintptr_t)big + 5 * NB * 2;              // m7/m8 region: 102 MB
    else         ibase = (uintptr_t)big + 3 * NB * 4;              // m4 region: 102 MB
    ibase = align_up(ibase, 256);
    int2* isw = (int2*)ibase;
    int*  idn = (int*)(ibase + (size_t)E * 8);

    // ---- CSR build (R6 proven form) ----
    hipMemsetAsync(counts, 0, (size_t)N_NODES * 4, stream);
    hist_kernel<<<eb, 256, 0, stream>>>(dst, counts, E);
    scan1<<<NBLK, 256, 0, stream>>>(counts, blockSum);
    scan2<<<1, 512, 0, stream>>>(blockSum);
    scan3<<<NBLK, 256, 0, stream>>>(counts, blockSum, rowStart);
    initcur_kernel<<<NBLK, 256, 0, stream>>>(rowStart, cursor, bcur);
    bucketize_kernel<<<(E + 256 * EPT - 1) / (256 * EPT), 256, 0, stream>>>(
        src, dst, ew, bcur, isw, idn, E);
    place_kernel<<<eb, 256, 0, stream>>>(isw, idn, cursor, csr_pair, E);

    if (schemeA) {
        // ---- scheme A: m1 fp32 in out slice 0; m2..m8 bf16 slice-major in ws ----
        unsigned short* m28 = (unsigned short*)big;
        float* m1 = out;  // slice 0

        hipMemsetAsync(col_of_node, 0xFF, (size_t)N_NODES * 4, stream);
        hipMemsetAsync(flag, 0, (size_t)N_NODES * 4, stream);
        hipMemsetAsync(m1, 0, NB * 4, stream);

        colmap_kernel<<<1, 256, 0, stream>>>(bi, col_of_node, next_dup);
        m1_edges_kernel<<<eb, 256, 0, stream>>>(src, dst, ew, col_of_node, next_dup,
                                                m1, flag, E);
        spmm_k2<<<nodeGrid, 256, 0, stream>>>(m1, m28, rowStart, counts, csr_pair, flag);
        for (int k = 3; k <= ORDER; ++k) {
            spmm_bf_slice2<<<SLICES * CHUNKS2, 256, 0, stream>>>(
                m28 + (size_t)(k - 3) * NB, m28 + (size_t)(k - 2) * NB,
                rowStart, counts, (const long long*)csr_pair);
        }
        combine_bf<<<cgrid, 256, 0, stream>>>(out, m28, coeffs, bi);
    } else {
        // ---- scheme B (fp32): m1..m4 in ws, m5..m8 in out; column-halved chain ----
        float* fbig = (float*)big;
        float* mpow[ORDER + 1];
        for (int k = 1; k <= 4; ++k) mpow[k] = fbig + (size_t)(k - 1) * NB;
        for (int k = 5; k <= 8; ++k) mpow[k] = out + (size_t)(k - 5) * NB;

        hipMemsetAsync(col_of_node, 0xFF, (size_t)N_NODES * 4, stream);
        hipMemsetAsync(flag, 0, (size_t)N_NODES * 4, stream);
        hipMemsetAsync(mpow[1], 0, NB * 4, stream);
        colmap_kernel<<<1, 256, 0, stream>>>(bi, col_of_node, next_dup);
        m1_edges_kernel<<<eb, 256, 0, stream>>>(src, dst, ew, col_of_node, next_dup,
                                                mpow[1], flag, E);
        for (int h = 0; h < 2; ++h) {
            int colOff = h * 128;
            for (int k = 2; k <= ORDER; ++k) {
                spmm_half<<<nodeGrid, 256, 0, stream>>>(mpow[k - 1], mpow[k],
                                                        rowStart, counts, csr_pair, colOff);
            }
        }
        combine_kernel<<<cgrid, 256, 0, stream>>>(out, fbig, coeffs, bi);
    }
}

// Round 10
// 1863.599 us; speedup vs baseline: 2.5316x; 2.5316x over previous
//
#include <hip/hip_runtime.h>

#define N_NODES 100000
#define BATCH   256
#define NUM_TAU 4
#define ORDER   8
#define NB      ((size_t)N_NODES * BATCH)   // 25,600,000 elements per tau slice
#define NBUK    98                          // buckets of 1024 nodes (id>>10)
#define EPT     16

__device__ __forceinline__ unsigned short f2bf(float f) {
    unsigned int u = __float_as_uint(f);
    u += 0x7FFFu + ((u >> 16) & 1u);   // round-to-nearest-even
    return (unsigned short)(u >> 16);
}
__device__ __forceinline__ float bf2f(unsigned short h) {
    return __uint_as_float((unsigned int)h << 16);
}

// ================= CSR build: LDS-atomic pipeline (no per-edge global atomics) =================

// pass 1: per-bucket edge counts (LDS histogram, 98 global atomics per block)
__global__ void bukhist_kernel(const int* __restrict__ dst, int* __restrict__ bukCnt, int E) {
    __shared__ int c[NBUK];
    for (int i = threadIdx.x; i < NBUK; i += 256) c[i] = 0;
    __syncthreads();
    int e0 = blockIdx.x * (256 * EPT);
    #pragma unroll
    for (int i = 0; i < EPT; ++i) {
        int e = e0 + i * 256 + threadIdx.x;
        if (e < E) atomicAdd(&c[dst[e] >> 10], 1);
    }
    __syncthreads();
    for (int i = threadIdx.x; i < NBUK; i += 256)
        if (c[i]) atomicAdd(&bukCnt[i], c[i]);
}

// pass 2: exclusive scan of 98 bucket counts -> bukBase[0..98], init bcur
__global__ void bukscan_kernel(const int* __restrict__ bukCnt, int* __restrict__ bukBase,
                               int* __restrict__ bcur, int E) {
    __shared__ int s[128];
    int t = threadIdx.x;
    int v = (t < NBUK) ? bukCnt[t] : 0;
    s[t] = v;
    __syncthreads();
    for (int st = 1; st < 128; st <<= 1) {
        int u = (t >= st) ? s[t - st] : 0;
        __syncthreads();
        s[t] += u;
        __syncthreads();
    }
    if (t < NBUK) { int ex = s[t] - v; bukBase[t] = ex; bcur[t] = ex; }
    if (t == 0) bukBase[NBUK] = E;
}

// pass 3: bucketize edges into exact per-bucket regions (LDS counts, bulk global reserve)
__global__ void bucketize_kernel(const int* __restrict__ src, const int* __restrict__ dst,
                                 const float* __restrict__ w, int* __restrict__ bcur,
                                 int2* __restrict__ isw, int* __restrict__ idn, int E) {
    __shared__ int cnt[NBUK], base[NBUK], off[NBUK];
    int e0 = blockIdx.x * (256 * EPT);
    for (int i = threadIdx.x; i < NBUK; i += 256) { cnt[i] = 0; off[i] = 0; }
    __syncthreads();
    #pragma unroll
    for (int i = 0; i < EPT; ++i) {
        int e = e0 + i * 256 + threadIdx.x;
        if (e < E) atomicAdd(&cnt[dst[e] >> 10], 1);
    }
    __syncthreads();
    for (int i = threadIdx.x; i < NBUK; i += 256) {
        int c = cnt[i];
        base[i] = c ? atomicAdd(&bcur[i], c) : 0;
    }
    __syncthreads();
    #pragma unroll
    for (int i = 0; i < EPT; ++i) {
        int e = e0 + i * 256 + threadIdx.x;
        if (e < E) {
            int d = dst[e];
            int b = d >> 10;
            int p = base[b] + atomicAdd(&off[b], 1);
            isw[p] = make_int2(src[e], __float_as_int(w[e]));
            idn[p] = d;
        }
    }
}

// pass 4: per-bucket CSR build — node hist + 1024-scan + placement all in LDS
__global__ void buildcsr_kernel(const int2* __restrict__ isw, const int* __restrict__ idn,
                                const int* __restrict__ bukBase,
                                int* __restrict__ counts, int* __restrict__ rowStart,
                                int2* __restrict__ csr_pair) {
    __shared__ int cnt[1024];
    __shared__ int part[256];
    int b = blockIdx.x;
    int n0 = b << 10;
    int nN = N_NODES - n0; if (nN > 1024) nN = 1024;
    int e0 = bukBase[b], e1 = bukBase[b + 1];
    int t = threadIdx.x;

    #pragma unroll
    for (int i = t; i < 1024; i += 256) cnt[i] = 0;
    __syncthreads();
    for (int e = e0 + t; e < e1; e += 256)
        atomicAdd(&cnt[idn[e] - n0], 1);
    __syncthreads();

    // per-thread sequential over its 4 slots
    int i0 = t * 4;
    int c0 = cnt[i0], c1 = cnt[i0 + 1], c2 = cnt[i0 + 2], c3 = cnt[i0 + 3];
    int sum = c0 + c1 + c2 + c3;
    part[t] = sum;
    __syncthreads();
    int v = sum;
    for (int st = 1; st < 256; st <<= 1) {
        int u = (t >= st) ? part[t - st] : 0;
        __syncthreads();
        part[t] += u;
        __syncthreads();
    }
    int ex = part[t] - v;  // exclusive offset of slot i0 within bucket

    int o0 = ex, o1 = ex + c0, o2 = o1 + c1, o3 = o2 + c2;
    // global counts + rowStart
    if (i0 + 0 < nN) { counts[n0 + i0 + 0] = c0; rowStart[n0 + i0 + 0] = e0 + o0; }
    if (i0 + 1 < nN) { counts[n0 + i0 + 1] = c1; rowStart[n0 + i0 + 1] = e0 + o1; }
    if (i0 + 2 < nN) { counts[n0 + i0 + 2] = c2; rowStart[n0 + i0 + 2] = e0 + o2; }
    if (i0 + 3 < nN) { counts[n0 + i0 + 3] = c3; rowStart[n0 + i0 + 3] = e0 + o3; }
    // reuse cnt[] as intra-bucket cursors
    cnt[i0] = o0; cnt[i0 + 1] = o1; cnt[i0 + 2] = o2; cnt[i0 + 3] = o3;
    __syncthreads();

    for (int e = e0 + t; e < e1; e += 256) {
        int d = idn[e];
        int p = e0 + atomicAdd(&cnt[d - n0], 1);
        csr_pair[p] = isw[e];
    }
}

// ================= sparse m1 = A @ onehot (m1 fp32, lives in out slice 0) =================

__global__ void colmap_kernel(const int* __restrict__ bi, int* __restrict__ col_of_node,
                              int* __restrict__ next_dup) {
    int j = threadIdx.x;  // 256
    int prev = atomicExch(&col_of_node[bi[j]], j);
    next_dup[j] = prev;
}

__global__ void m1_edges_kernel(const int* __restrict__ src, const int* __restrict__ dst,
                                const float* __restrict__ w,
                                const int* __restrict__ col_of_node,
                                const int* __restrict__ next_dup,
                                float* __restrict__ m1, int* __restrict__ flag, int E) {
    int e = blockIdx.x * blockDim.x + threadIdx.x;
    if (e >= E) return;
    int j = col_of_node[src[e]];
    if (j < 0) return;
    float we = w[e];
    int d = dst[e];
    flag[d] = 1;
    size_t rb = (size_t)d * BATCH;
    while (j >= 0) {
        atomicAdd(&m1[rb + j], we);
        j = next_dup[j];
    }
}

// ================= k=2: fp32 m1 (flag-skipped) -> bf16 m2 (row-major) =================
__global__ void spmm_k2(const float* __restrict__ m1, unsigned short* __restrict__ m2,
                        const int* __restrict__ rowStart, const int* __restrict__ counts,
                        const int2* __restrict__ csr_pair, const int* __restrict__ flag) {
    int wave = threadIdx.x >> 6;
    int lane = threadIdx.x & 63;
    int node = blockIdx.x * 4 + wave;
    if (node >= N_NODES) return;
    int col0 = lane * 4;

    int start = rowStart[node];
    int len   = counts[node];

    float4 acc = make_float4(0.f, 0.f, 0.f, 0.f);
    for (int i = 0; i < len; ++i) {
        int2 pr = csr_pair[start + i];
        if (flag[pr.x]) {
            float w = __int_as_float(pr.y);
            float4 v = *(const float4*)(m1 + (size_t)pr.x * BATCH + col0);
            acc.x += w * v.x; acc.y += w * v.y; acc.z += w * v.z; acc.w += w * v.w;
        }
    }
    ushort4 o;
    o.x = f2bf(acc.x); o.y = f2bf(acc.y); o.z = f2bf(acc.z); o.w = f2bf(acc.w);
    *(ushort4*)(m2 + (size_t)node * BATCH + col0) = o;
}

// ================= bf16 -> bf16 SpMM, 8-deep gather pipeline (R6 proven) =================
__global__ void spmm_bf(const unsigned short* __restrict__ min_, unsigned short* __restrict__ mout,
                        const int* __restrict__ rowStart, const int* __restrict__ counts,
                        const int2* __restrict__ csr_pair) {
    int wave = threadIdx.x >> 6;
    int lane = threadIdx.x & 63;
    int node = blockIdx.x * 4 + wave;
    if (node >= N_NODES) return;
    int col0 = lane * 4;

    int start = rowStart[node];
    int len   = counts[node];

    float4 acc = make_float4(0.f, 0.f, 0.f, 0.f);
    int i = 0;
    for (; i + 8 <= len; i += 8) {
        int2 pr[8];
        #pragma unroll
        for (int u = 0; u < 8; ++u) pr[u] = csr_pair[start + i + u];
        ushort4 v[8];
        #pragma unroll
        for (int u = 0; u < 8; ++u)
            v[u] = *(const ushort4*)(min_ + (size_t)pr[u].x * BATCH + col0);
        #pragma unroll
        for (int u = 0; u < 8; ++u) {
            float w = __int_as_float(pr[u].y);
            acc.x += w * bf2f(v[u].x);
            acc.y += w * bf2f(v[u].y);
            acc.z += w * bf2f(v[u].z);
            acc.w += w * bf2f(v[u].w);
        }
    }
    for (; i < len; ++i) {
        int2 pr = csr_pair[start + i];
        float w = __int_as_float(pr.y);
        ushort4 v = *(const ushort4*)(min_ + (size_t)pr.x * BATCH + col0);
        acc.x += w * bf2f(v.x);
        acc.y += w * bf2f(v.y);
        acc.z += w * bf2f(v.z);
        acc.w += w * bf2f(v.w);
    }
    ushort4 o;
    o.x = f2bf(acc.x); o.y = f2bf(acc.y); o.z = f2bf(acc.z); o.w = f2bf(acc.w);
    *(ushort4*)(mout + (size_t)node * BATCH + col0) = o;
}

// ================= fused last hop: m8 in regs + full polynomial epilogue =================
// m27: big (idx 0..5 = m2..m7 bf16 row-major). m1 fp32 at out slice 0 (flag-gated, in-place read).
__global__ void spmm_bf_last(const unsigned short* __restrict__ m27,
                             const int* __restrict__ rowStart, const int* __restrict__ counts,
                             const int2* __restrict__ csr_pair,
                             const float* __restrict__ coeffs, const int* __restrict__ flag,
                             float* __restrict__ out, const int* __restrict__ bi) {
    int wave = threadIdx.x >> 6;
    int lane = threadIdx.x & 63;
    int node = blockIdx.x * 4 + wave;
    if (node >= N_NODES) return;
    int col0 = lane * 4;

    int start = rowStart[node];
    int len   = counts[node];
    const unsigned short* m7 = m27 + 5 * NB;

    float4 acc = make_float4(0.f, 0.f, 0.f, 0.f);
    int i = 0;
    for (; i + 8 <= len; i += 8) {
        int2 pr[8];
        #pragma unroll
        for (int u = 0; u < 8; ++u) pr[u] = csr_pair[start + i + u];
        ushort4 v[8];
        #pragma unroll
        for (int u = 0; u < 8; ++u)
            v[u] = *(const ushort4*)(m7 + (size_t)pr[u].x * BATCH + col0);
        #pragma unroll
        for (int u = 0; u < 8; ++u) {
            float w = __int_as_float(pr[u].y);
            acc.x += w * bf2f(v[u].x);
            acc.y += w * bf2f(v[u].y);
            acc.z += w * bf2f(v[u].z);
            acc.w += w * bf2f(v[u].w);
        }
    }
    for (; i < len; ++i) {
        int2 pr = csr_pair[start + i];
        float w = __int_as_float(pr.y);
        ushort4 v = *(const ushort4*)(m7 + (size_t)pr.x * BATCH + col0);
        acc.x += w * bf2f(v.x);
        acc.y += w * bf2f(v.y);
        acc.z += w * bf2f(v.z);
        acc.w += w * bf2f(v.w);
    }

    // epilogue: out[t] = c[t,0]*onehot + sum_k c[t,k]*m_k  (m8 = acc)
    size_t base = (size_t)node * BATCH + col0;
    float4 p[ORDER];
    if (flag[node]) p[0] = *(const float4*)(out + base);   // m1 (in-place, own cells only)
    else            p[0] = make_float4(0.f, 0.f, 0.f, 0.f);
    #pragma unroll
    for (int k = 2; k <= 7; ++k) {
        ushort4 v = *(const ushort4*)(m27 + (size_t)(k - 2) * NB + base);
        p[k - 1] = make_float4(bf2f(v.x), bf2f(v.y), bf2f(v.z), bf2f(v.w));
    }
    p[7] = acc;

    float oh[4];
    #pragma unroll
    for (int q = 0; q < 4; ++q) oh[q] = (bi[col0 + q] == node) ? 1.0f : 0.0f;

    #pragma unroll
    for (int t = 0; t < NUM_TAU; ++t) {
        float c0 = coeffs[t * (ORDER + 1)];
        float4 o = make_float4(c0 * oh[0], c0 * oh[1], c0 * oh[2], c0 * oh[3]);
        #pragma unroll
        for (int k = 1; k <= ORDER; ++k) {
            float c = coeffs[t * (ORDER + 1) + k];
            o.x += c * p[k - 1].x;
            o.y += c * p[k - 1].y;
            o.z += c * p[k - 1].z;
            o.w += c * p[k - 1].w;
        }
        *(float4*)(out + (size_t)t * NB + base) = o;
    }
}

// ================= fallback scheme B (fp32 path, row-major) =================

__global__ void spmm_half(const float* __restrict__ min_, float* __restrict__ mout,
                          const int* __restrict__ rowStart, const int* __restrict__ counts,
                          const int2* __restrict__ csr_pair, int colOff) {
    int wave = threadIdx.x >> 6;
    int lane = threadIdx.x & 63;
    int node = blockIdx.x * 4 + wave;
    if (node >= N_NODES) return;
    int c = colOff + lane * 2;
    int start = rowStart[node];
    int len   = counts[node];
    float2 acc = make_float2(0.f, 0.f);
    int i = 0;
    for (; i + 8 <= len; i += 8) {
        int2 pr[8];
        #pragma unroll
        for (int u = 0; u < 8; ++u) pr[u] = csr_pair[start + i + u];
        float2 v[8];
        #pragma unroll
        for (int u = 0; u < 8; ++u)
            v[u] = *(const float2*)(min_ + (size_t)pr[u].x * BATCH + c);
        #pragma unroll
        for (int u = 0; u < 8; ++u) {
            float w = __int_as_float(pr[u].y);
            acc.x += w * v[u].x;
            acc.y += w * v[u].y;
        }
    }
    for (; i < len; ++i) {
        int2 pr = csr_pair[start + i];
        float w = __int_as_float(pr.y);
        float2 v = *(const float2*)(min_ + (size_t)pr.x * BATCH + c);
        acc.x += w * v.x;
        acc.y += w * v.y;
    }
    *(float2*)(mout + (size_t)node * BATCH + c) = acc;
}

__global__ void combine_kernel(float* __restrict__ out, const float* __restrict__ m14,
                               const float* __restrict__ coeffs, const int* __restrict__ bi) {
    size_t tid = (size_t)blockIdx.x * blockDim.x + threadIdx.x;
    size_t base = tid * 4;
    if (base >= NB) return;
    int node = (int)(base >> 8);
    int j0   = (int)(base & 255);
    float4 p[ORDER];
    #pragma unroll
    for (int k = 1; k <= 4; ++k)
        p[k - 1] = *(const float4*)(m14 + (size_t)(k - 1) * NB + base);
    #pragma unroll
    for (int k = 5; k <= 8; ++k)
        p[k - 1] = *(const float4*)(out + (size_t)(k - 5) * NB + base);
    float oh[4];
    #pragma unroll
    for (int i = 0; i < 4; ++i) oh[i] = (bi[j0 + i] == node) ? 1.0f : 0.0f;
    #pragma unroll
    for (int t = 0; t < NUM_TAU; ++t) {
        float c0 = coeffs[t * (ORDER + 1)];
        float4 o = make_float4(c0 * oh[0], c0 * oh[1], c0 * oh[2], c0 * oh[3]);
        #pragma unroll
        for (int k = 1; k <= ORDER; ++k) {
            float c = coeffs[t * (ORDER + 1) + k];
            o.x += c * p[k - 1].x;
            o.y += c * p[k - 1].y;
            o.z += c * p[k - 1].z;
            o.w += c * p[k - 1].w;
        }
        *(float4*)(out + (size_t)t * NB + base) = o;
    }
}

extern "C" void kernel_launch(void* const* d_in, const int* in_sizes, int n_in,
                              void* d_out, int out_size, void* d_ws, size_t ws_size,
                              hipStream_t stream) {
    const float* coeffs = (const float*)d_in[0];
    const float* ew     = (const float*)d_in[1];
    const int*   src    = (const int*)d_in[2];
    const int*   dst    = (const int*)d_in[3];
    const int*   bi     = (const int*)d_in[4];   // int32 on device (JAX x64 disabled)
    const int E = in_sizes[1];

    float* out = (float*)d_out;

    auto align_up = [](uintptr_t v, uintptr_t a) { return (v + a - 1) & ~(a - 1); };

    uintptr_t p0 = (uintptr_t)d_ws;
    int* counts      = (int*)p0;  p0 += (size_t)N_NODES * 4;  p0 = align_up(p0, 256);
    int* rowStart    = (int*)p0;  p0 += (size_t)N_NODES * 4;  p0 = align_up(p0, 256);
    int* bukCnt      = (int*)p0;  p0 += (size_t)NBUK * 4;     p0 = align_up(p0, 256);
    int* bukBase     = (int*)p0;  p0 += (size_t)(NBUK + 1) * 4; p0 = align_up(p0, 256);
    int* bcur        = (int*)p0;  p0 += (size_t)NBUK * 4;     p0 = align_up(p0, 256);
    int* col_of_node = (int*)p0;  p0 += (size_t)N_NODES * 4;  p0 = align_up(p0, 256);
    int* next_dup    = (int*)p0;  p0 += 1024;                 p0 = align_up(p0, 256);
    int* flag        = (int*)p0;  p0 += (size_t)N_NODES * 4;  p0 = align_up(p0, 256);
    int2* csr_pair   = (int2*)p0; p0 += (size_t)E * 8;        p0 = align_up(p0, 256);
    void* big        = (void*)p0;
    size_t big_bytes = ((uintptr_t)d_ws + ws_size > p0) ? ((uintptr_t)d_ws + ws_size - p0) : 0;

    int eb = (E + 255) / 256;
    int ebt = (E + 256 * EPT - 1) / (256 * EPT);
    int nodeGrid = (N_NODES + 3) / 4;
    int cgrid = (int)((NB / 4 + 255) / 256);

    // intermediate bucket-grouped edge buffer overlays the tail of `big`
    // (region only written by late spmm hops, long after buildcsr completes).
    bool schemeA = (big_bytes >= 6 * NB * 2);
    uintptr_t ibase;
    if (schemeA) ibase = (uintptr_t)big + 4 * NB * 2;   // m6/m7 region (102 MB)
    else         ibase = (uintptr_t)big + 3 * NB * 4;   // m4 region (102 MB)
    ibase = align_up(ibase, 256);
    int2* isw = (int2*)ibase;
    int*  idn = (int*)(ibase + (size_t)E * 8);

    // ---- CSR build (LDS-atomic pipeline) ----
    hipMemsetAsync(bukCnt, 0, (size_t)NBUK * 4, stream);
    bukhist_kernel<<<ebt, 256, 0, stream>>>(dst, bukCnt, E);
    bukscan_kernel<<<1, 128, 0, stream>>>(bukCnt, bukBase, bcur, E);
    bucketize_kernel<<<ebt, 256, 0, stream>>>(src, dst, ew, bcur, isw, idn, E);
    buildcsr_kernel<<<NBUK, 256, 0, stream>>>(isw, idn, bukBase, counts, rowStart, csr_pair);

    if (schemeA) {
        // ---- scheme A: m1 fp32 in out slice 0; m2..m7 bf16 in ws; fused last hop ----
        unsigned short* m27 = (unsigned short*)big;
        float* m1 = out;  // slice 0

        hipMemsetAsync(col_of_node, 0xFF, (size_t)N_NODES * 4, stream);
        hipMemsetAsync(flag, 0, (size_t)N_NODES * 4, stream);
        hipMemsetAsync(m1, 0, NB * 4, stream);

        colmap_kernel<<<1, 256, 0, stream>>>(bi, col_of_node, next_dup);
        m1_edges_kernel<<<eb, 256, 0, stream>>>(src, dst, ew, col_of_node, next_dup,
                                                m1, flag, E);
        spmm_k2<<<nodeGrid, 256, 0, stream>>>(m1, m27, rowStart, counts, csr_pair, flag);
        for (int k = 3; k <= 7; ++k) {
            spmm_bf<<<nodeGrid, 256, 0, stream>>>(m27 + (size_t)(k - 3) * NB,
                                                  m27 + (size_t)(k - 2) * NB,
                                                  rowStart, counts, csr_pair);
        }
        spmm_bf_last<<<nodeGrid, 256, 0, stream>>>(m27, rowStart, counts, csr_pair,
                                                   coeffs, flag, out, bi);
    } else {
        // ---- scheme B (fp32): m1..m4 in ws, m5..m8 in out; column-halved chain ----
        float* fbig = (float*)big;
        float* mpow[ORDER + 1];
        for (int k = 1; k <= 4; ++k) mpow[k] = fbig + (size_t)(k - 1) * NB;
        for (int k = 5; k <= 8; ++k) mpow[k] = out + (size_t)(k - 5) * NB;

        hipMemsetAsync(col_of_node, 0xFF, (size_t)N_NODES * 4, stream);
        hipMemsetAsync(flag, 0, (size_t)N_NODES * 4, stream);
        hipMemsetAsync(mpow[1], 0, NB * 4, stream);
        colmap_kernel<<<1, 256, 0, stream>>>(bi, col_of_node, next_dup);
        m1_edges_kernel<<<eb, 256, 0, stream>>>(src, dst, ew, col_of_node, next_dup,
                                                mpow[1], flag, E);
        for (int h = 0; h < 2; ++h) {
            int colOff = h * 128;
            for (int k = 2; k <= ORDER; ++k) {
                spmm_half<<<nodeGrid, 256, 0, stream>>>(mpow[k - 1], mpow[k],
                                                        rowStart, counts, csr_pair, colOff);
            }
        }
        combine_kernel<<<cgrid, 256, 0, stream>>>(out, fbig, coeffs, bi);
    }
}

// Round 12
// 1814.425 us; speedup vs baseline: 2.6002x; 1.0271x over previous
//
#include <hip/hip_runtime.h>

#define N_NODES 100000
#define BATCH   256
#define NUM_TAU 4
#define ORDER   8
#define NB      ((size_t)N_NODES * BATCH)   // 25,600,000 elements per tau slice
#define NBUK    98                          // buckets of 1024 nodes (id>>10)
#define EPT     16

typedef float f32x4 __attribute__((ext_vector_type(4)));

__device__ __forceinline__ unsigned short f2bf(float f) {
    unsigned int u = __float_as_uint(f);
    u += 0x7FFFu + ((u >> 16) & 1u);   // round-to-nearest-even
    return (unsigned short)(u >> 16);
}
__device__ __forceinline__ float bf2f(unsigned short h) {
    return __uint_as_float((unsigned int)h << 16);
}

// ================= CSR build: LDS-atomic pipeline (R10 proven) =================

__global__ void bukhist_kernel(const int* __restrict__ dst, int* __restrict__ bukCnt, int E) {
    __shared__ int c[NBUK];
    for (int i = threadIdx.x; i < NBUK; i += 256) c[i] = 0;
    __syncthreads();
    int e0 = blockIdx.x * (256 * EPT);
    #pragma unroll
    for (int i = 0; i < EPT; ++i) {
        int e = e0 + i * 256 + threadIdx.x;
        if (e < E) atomicAdd(&c[dst[e] >> 10], 1);
    }
    __syncthreads();
    for (int i = threadIdx.x; i < NBUK; i += 256)
        if (c[i]) atomicAdd(&bukCnt[i], c[i]);
}

__global__ void bukscan_kernel(const int* __restrict__ bukCnt, int* __restrict__ bukBase,
                               int* __restrict__ bcur, int E) {
    __shared__ int s[128];
    int t = threadIdx.x;
    int v = (t < NBUK) ? bukCnt[t] : 0;
    s[t] = v;
    __syncthreads();
    for (int st = 1; st < 128; st <<= 1) {
        int u = (t >= st) ? s[t - st] : 0;
        __syncthreads();
        s[t] += u;
        __syncthreads();
    }
    if (t < NBUK) { int ex = s[t] - v; bukBase[t] = ex; bcur[t] = ex; }
    if (t == 0) bukBase[NBUK] = E;
}

__global__ void bucketize_kernel(const int* __restrict__ src, const int* __restrict__ dst,
                                 const float* __restrict__ w, int* __restrict__ bcur,
                                 int2* __restrict__ isw, int* __restrict__ idn, int E) {
    __shared__ int cnt[NBUK], base[NBUK], off[NBUK];
    int e0 = blockIdx.x * (256 * EPT);
    for (int i = threadIdx.x; i < NBUK; i += 256) { cnt[i] = 0; off[i] = 0; }
    __syncthreads();
    #pragma unroll
    for (int i = 0; i < EPT; ++i) {
        int e = e0 + i * 256 + threadIdx.x;
        if (e < E) atomicAdd(&cnt[dst[e] >> 10], 1);
    }
    __syncthreads();
    for (int i = threadIdx.x; i < NBUK; i += 256) {
        int c = cnt[i];
        base[i] = c ? atomicAdd(&bcur[i], c) : 0;
    }
    __syncthreads();
    #pragma unroll
    for (int i = 0; i < EPT; ++i) {
        int e = e0 + i * 256 + threadIdx.x;
        if (e < E) {
            int d = dst[e];
            int b = d >> 10;
            int p = base[b] + atomicAdd(&off[b], 1);
            isw[p] = make_int2(src[e], __float_as_int(w[e]));
            idn[p] = d;
        }
    }
}

__global__ void buildcsr_kernel(const int2* __restrict__ isw, const int* __restrict__ idn,
                                const int* __restrict__ bukBase,
                                int* __restrict__ counts, int* __restrict__ rowStart,
                                int2* __restrict__ csr_pair) {
    __shared__ int cnt[1024];
    __shared__ int part[256];
    int b = blockIdx.x;
    int n0 = b << 10;
    int nN = N_NODES - n0; if (nN > 1024) nN = 1024;
    int e0 = bukBase[b], e1 = bukBase[b + 1];
    int t = threadIdx.x;

    #pragma unroll
    for (int i = t; i < 1024; i += 256) cnt[i] = 0;
    __syncthreads();
    for (int e = e0 + t; e < e1; e += 256)
        atomicAdd(&cnt[idn[e] - n0], 1);
    __syncthreads();

    int i0 = t * 4;
    int c0 = cnt[i0], c1 = cnt[i0 + 1], c2 = cnt[i0 + 2], c3 = cnt[i0 + 3];
    int sum = c0 + c1 + c2 + c3;
    part[t] = sum;
    __syncthreads();
    int v = sum;
    for (int st = 1; st < 256; st <<= 1) {
        int u = (t >= st) ? part[t - st] : 0;
        __syncthreads();
        part[t] += u;
        __syncthreads();
    }
    int ex = part[t] - v;

    int o0 = ex, o1 = ex + c0, o2 = o1 + c1, o3 = o2 + c2;
    if (i0 + 0 < nN) { counts[n0 + i0 + 0] = c0; rowStart[n0 + i0 + 0] = e0 + o0; }
    if (i0 + 1 < nN) { counts[n0 + i0 + 1] = c1; rowStart[n0 + i0 + 1] = e0 + o1; }
    if (i0 + 2 < nN) { counts[n0 + i0 + 2] = c2; rowStart[n0 + i0 + 2] = e0 + o2; }
    if (i0 + 3 < nN) { counts[n0 + i0 + 3] = c3; rowStart[n0 + i0 + 3] = e0 + o3; }
    cnt[i0] = o0; cnt[i0 + 1] = o1; cnt[i0 + 2] = o2; cnt[i0 + 3] = o3;
    __syncthreads();

    for (int e = e0 + t; e < e1; e += 256) {
        int d = idn[e];
        int p = e0 + atomicAdd(&cnt[d - n0], 1);
        csr_pair[p] = isw[e];
    }
}

// ================= sparse m1 = A @ onehot (m1 fp32, lives in out slice 0) =================

__global__ void colmap_kernel(const int* __restrict__ bi, int* __restrict__ col_of_node,
                              int* __restrict__ next_dup) {
    int j = threadIdx.x;  // 256
    int prev = atomicExch(&col_of_node[bi[j]], j);
    next_dup[j] = prev;
}

__global__ void m1_edges_kernel(const int* __restrict__ src, const int* __restrict__ dst,
                                const float* __restrict__ w,
                                const int* __restrict__ col_of_node,
                                const int* __restrict__ next_dup,
                                float* __restrict__ m1, int* __restrict__ flag, int E) {
    int e = blockIdx.x * blockDim.x + threadIdx.x;
    if (e >= E) return;
    int j = col_of_node[src[e]];
    if (j < 0) return;
    float we = w[e];
    int d = dst[e];
    flag[d] = 1;
    size_t rb = (size_t)d * BATCH;
    while (j >= 0) {
        atomicAdd(&m1[rb + j], we);
        j = next_dup[j];
    }
}

// ================= k=2: fp32 m1 (flag-skipped) -> bf16 m2 (row-major) =================
__global__ void spmm_k2(const float* __restrict__ m1, unsigned short* __restrict__ m2,
                        const int* __restrict__ rowStart, const int* __restrict__ counts,
                        const int2* __restrict__ csr_pair, const int* __restrict__ flag) {
    int wave = threadIdx.x >> 6;
    int lane = threadIdx.x & 63;
    int node = blockIdx.x * 4 + wave;
    if (node >= N_NODES) return;
    int col0 = lane * 4;

    int start = __builtin_amdgcn_readfirstlane(rowStart[node]);
    int len   = __builtin_amdgcn_readfirstlane(counts[node]);
    const int2* cp = csr_pair + start;   // wave-uniform base -> scalar loads

    float4 acc = make_float4(0.f, 0.f, 0.f, 0.f);
    for (int i = 0; i < len; ++i) {
        int2 pr = cp[i];
        if (flag[pr.x]) {
            float w = __int_as_float(pr.y);
            float4 v = *(const float4*)(m1 + (size_t)pr.x * BATCH + col0);
            acc.x += w * v.x; acc.y += w * v.y; acc.z += w * v.z; acc.w += w * v.w;
        }
    }
    ushort4 o;
    o.x = f2bf(acc.x); o.y = f2bf(acc.y); o.z = f2bf(acc.z); o.w = f2bf(acc.w);
    *(ushort4*)(m2 + (size_t)node * BATCH + col0) = o;
}

// ================= bf16 -> bf16 SpMM, 8-deep gather pipeline, scalar csr =================
__global__ void spmm_bf(const unsigned short* __restrict__ min_, unsigned short* __restrict__ mout,
                        const int* __restrict__ rowStart, const int* __restrict__ counts,
                        const int2* __restrict__ csr_pair) {
    int wave = threadIdx.x >> 6;
    int lane = threadIdx.x & 63;
    int node = blockIdx.x * 4 + wave;
    if (node >= N_NODES) return;
    int col0 = lane * 4;

    int start = __builtin_amdgcn_readfirstlane(rowStart[node]);
    int len   = __builtin_amdgcn_readfirstlane(counts[node]);
    const int2* cp = csr_pair + start;   // wave-uniform base -> scalar loads

    float4 acc = make_float4(0.f, 0.f, 0.f, 0.f);
    int i = 0;
    for (; i + 8 <= len; i += 8) {
        int2 pr[8];
        #pragma unroll
        for (int u = 0; u < 8; ++u) pr[u] = cp[i + u];
        ushort4 v[8];
        #pragma unroll
        for (int u = 0; u < 8; ++u)
            v[u] = *(const ushort4*)(min_ + (size_t)pr[u].x * BATCH + col0);
        #pragma unroll
        for (int u = 0; u < 8; ++u) {
            float w = __int_as_float(pr[u].y);
            acc.x += w * bf2f(v[u].x);
            acc.y += w * bf2f(v[u].y);
            acc.z += w * bf2f(v[u].z);
            acc.w += w * bf2f(v[u].w);
        }
    }
    for (; i < len; ++i) {
        int2 pr = cp[i];
        float w = __int_as_float(pr.y);
        ushort4 v = *(const ushort4*)(min_ + (size_t)pr.x * BATCH + col0);
        acc.x += w * bf2f(v.x);
        acc.y += w * bf2f(v.y);
        acc.z += w * bf2f(v.z);
        acc.w += w * bf2f(v.w);
    }
    ushort4 o;
    o.x = f2bf(acc.x); o.y = f2bf(acc.y); o.z = f2bf(acc.z); o.w = f2bf(acc.w);
    *(ushort4*)(mout + (size_t)node * BATCH + col0) = o;
}

// ================= fused last hop: m8 in regs + polynomial epilogue (nt out stores) =================
__global__ void spmm_bf_last(const unsigned short* __restrict__ m27,
                             const int* __restrict__ rowStart, const int* __restrict__ counts,
                             const int2* __restrict__ csr_pair,
                             const float* __restrict__ coeffs, const int* __restrict__ flag,
                             float* __restrict__ out, const int* __restrict__ bi) {
    int wave = threadIdx.x >> 6;
    int lane = threadIdx.x & 63;
    int node = blockIdx.x * 4 + wave;
    if (node >= N_NODES) return;
    int col0 = lane * 4;

    int start = __builtin_amdgcn_readfirstlane(rowStart[node]);
    int len   = __builtin_amdgcn_readfirstlane(counts[node]);
    const int2* cp = csr_pair + start;
    const unsigned short* m7 = m27 + 5 * NB;

    float4 acc = make_float4(0.f, 0.f, 0.f, 0.f);
    int i = 0;
    for (; i + 8 <= len; i += 8) {
        int2 pr[8];
        #pragma unroll
        for (int u = 0; u < 8; ++u) pr[u] = cp[i + u];
        ushort4 v[8];
        #pragma unroll
        for (int u = 0; u < 8; ++u)
            v[u] = *(const ushort4*)(m7 + (size_t)pr[u].x * BATCH + col0);
        #pragma unroll
        for (int u = 0; u < 8; ++u) {
            float w = __int_as_float(pr[u].y);
            acc.x += w * bf2f(v[u].x);
            acc.y += w * bf2f(v[u].y);
            acc.z += w * bf2f(v[u].z);
            acc.w += w * bf2f(v[u].w);
        }
    }
    for (; i < len; ++i) {
        int2 pr = cp[i];
        float w = __int_as_float(pr.y);
        ushort4 v = *(const ushort4*)(m7 + (size_t)pr.x * BATCH + col0);
        acc.x += w * bf2f(v.x);
        acc.y += w * bf2f(v.y);
        acc.z += w * bf2f(v.z);
        acc.w += w * bf2f(v.w);
    }

    size_t base = (size_t)node * BATCH + col0;
    float4 p[ORDER];
    if (flag[node]) p[0] = *(const float4*)(out + base);
    else            p[0] = make_float4(0.f, 0.f, 0.f, 0.f);
    #pragma unroll
    for (int k = 2; k <= 7; ++k) {
        ushort4 v = *(const ushort4*)(m27 + (size_t)(k - 2) * NB + base);
        p[k - 1] = make_float4(bf2f(v.x), bf2f(v.y), bf2f(v.z), bf2f(v.w));
    }
    p[7] = acc;

    float oh[4];
    #pragma unroll
    for (int q = 0; q < 4; ++q) oh[q] = (bi[col0 + q] == node) ? 1.0f : 0.0f;

    #pragma unroll
    for (int t = 0; t < NUM_TAU; ++t) {
        float c0 = coeffs[t * (ORDER + 1)];
        float4 o = make_float4(c0 * oh[0], c0 * oh[1], c0 * oh[2], c0 * oh[3]);
        #pragma unroll
        for (int k = 1; k <= ORDER; ++k) {
            float c = coeffs[t * (ORDER + 1) + k];
            o.x += c * p[k - 1].x;
            o.y += c * p[k - 1].y;
            o.z += c * p[k - 1].z;
            o.w += c * p[k - 1].w;
        }
        f32x4 ov = {o.x, o.y, o.z, o.w};
        __builtin_nontemporal_store(ov, (f32x4*)(out + (size_t)t * NB + base));
    }
}

// ================= fallback scheme B (fp32 path, row-major) =================

__global__ void spmm_half(const float* __restrict__ min_, float* __restrict__ mout,
                          const int* __restrict__ rowStart, const int* __restrict__ counts,
                          const int2* __restrict__ csr_pair, int colOff) {
    int wave = threadIdx.x >> 6;
    int lane = threadIdx.x & 63;
    int node = blockIdx.x * 4 + wave;
    if (node >= N_NODES) return;
    int c = colOff + lane * 2;
    int start = rowStart[node];
    int len   = counts[node];
    float2 acc = make_float2(0.f, 0.f);
    int i = 0;
    for (; i + 8 <= len; i += 8) {
        int2 pr[8];
        #pragma unroll
        for (int u = 0; u < 8; ++u) pr[u] = csr_pair[start + i + u];
        float2 v[8];
        #pragma unroll
        for (int u = 0; u < 8; ++u)
            v[u] = *(const float2*)(min_ + (size_t)pr[u].x * BATCH + c);
        #pragma unroll
        for (int u = 0; u < 8; ++u) {
            float w = __int_as_float(pr[u].y);
            acc.x += w * v[u].x;
            acc.y += w * v[u].y;
        }
    }
    for (; i < len; ++i) {
        int2 pr = csr_pair[start + i];
        float w = __int_as_float(pr.y);
        float2 v = *(const float2*)(min_ + (size_t)pr.x * BATCH + c);
        acc.x += w * v.x;
        acc.y += w * v.y;
    }
    *(float2*)(mout + (size_t)node * BATCH + c) = acc;
}

__global__ void combine_kernel(float* __restrict__ out, const float* __restrict__ m14,
                               const float* __restrict__ coeffs, const int* __restrict__ bi) {
    size_t tid = (size_t)blockIdx.x * blockDim.x + threadIdx.x;
    size_t base = tid * 4;
    if (base >= NB) return;
    int node = (int)(base >> 8);
    int j0   = (int)(base & 255);
    float4 p[ORDER];
    #pragma unroll
    for (int k = 1; k <= 4; ++k)
        p[k - 1] = *(const float4*)(m14 + (size_t)(k - 1) * NB + base);
    #pragma unroll
    for (int k = 5; k <= 8; ++k)
        p[k - 1] = *(const float4*)(out + (size_t)(k - 5) * NB + base);
    float oh[4];
    #pragma unroll
    for (int i = 0; i < 4; ++i) oh[i] = (bi[j0 + i] == node) ? 1.0f : 0.0f;
    #pragma unroll
    for (int t = 0; t < NUM_TAU; ++t) {
        float c0 = coeffs[t * (ORDER + 1)];
        float4 o = make_float4(c0 * oh[0], c0 * oh[1], c0 * oh[2], c0 * oh[3]);
        #pragma unroll
        for (int k = 1; k <= ORDER; ++k) {
            float c = coeffs[t * (ORDER + 1) + k];
            o.x += c * p[k - 1].x;
            o.y += c * p[k - 1].y;
            o.z += c * p[k - 1].z;
            o.w += c * p[k - 1].w;
        }
        *(float4*)(out + (size_t)t * NB + base) = o;
    }
}

extern "C" void kernel_launch(void* const* d_in, const int* in_sizes, int n_in,
                              void* d_out, int out_size, void* d_ws, size_t ws_size,
                              hipStream_t stream) {
    const float* coeffs = (const float*)d_in[0];
    const float* ew     = (const float*)d_in[1];
    const int*   src    = (const int*)d_in[2];
    const int*   dst    = (const int*)d_in[3];
    const int*   bi     = (const int*)d_in[4];   // int32 on device (JAX x64 disabled)
    const int E = in_sizes[1];

    float* out = (float*)d_out;

    auto align_up = [](uintptr_t v, uintptr_t a) { return (v + a - 1) & ~(a - 1); };

    uintptr_t p0 = (uintptr_t)d_ws;
    int* counts      = (int*)p0;  p0 += (size_t)N_NODES * 4;  p0 = align_up(p0, 256);
    int* rowStart    = (int*)p0;  p0 += (size_t)N_NODES * 4;  p0 = align_up(p0, 256);
    int* bukCnt      = (int*)p0;  p0 += (size_t)NBUK * 4;     p0 = align_up(p0, 256);
    int* bukBase     = (int*)p0;  p0 += (size_t)(NBUK + 1) * 4; p0 = align_up(p0, 256);
    int* bcur        = (int*)p0;  p0 += (size_t)NBUK * 4;     p0 = align_up(p0, 256);
    int* col_of_node = (int*)p0;  p0 += (size_t)N_NODES * 4;  p0 = align_up(p0, 256);
    int* next_dup    = (int*)p0;  p0 += 1024;                 p0 = align_up(p0, 256);
    int* flag        = (int*)p0;  p0 += (size_t)N_NODES * 4;  p0 = align_up(p0, 256);
    int2* csr_pair   = (int2*)p0; p0 += (size_t)E * 8;        p0 = align_up(p0, 256);
    void* big        = (void*)p0;
    size_t big_bytes = ((uintptr_t)d_ws + ws_size > p0) ? ((uintptr_t)d_ws + ws_size - p0) : 0;

    int eb = (E + 255) / 256;
    int ebt = (E + 256 * EPT - 1) / (256 * EPT);
    int nodeGrid = (N_NODES + 3) / 4;
    int cgrid = (int)((NB / 4 + 255) / 256);

    bool schemeA = (big_bytes >= 6 * NB * 2);
    uintptr_t ibase;
    if (schemeA) ibase = (uintptr_t)big + 4 * NB * 2;   // m6/m7 region (102 MB)
    else         ibase = (uintptr_t)big + 3 * NB * 4;   // m4 region (102 MB)
    ibase = align_up(ibase, 256);
    int2* isw = (int2*)ibase;
    int*  idn = (int*)(ibase + (size_t)E * 8);

    // ---- CSR build (LDS-atomic pipeline) ----
    (void)hipMemsetAsync(bukCnt, 0, (size_t)NBUK * 4, stream);
    bukhist_kernel<<<ebt, 256, 0, stream>>>(dst, bukCnt, E);
    bukscan_kernel<<<1, 128, 0, stream>>>(bukCnt, bukBase, bcur, E);
    bucketize_kernel<<<ebt, 256, 0, stream>>>(src, dst, ew, bcur, isw, idn, E);
    buildcsr_kernel<<<NBUK, 256, 0, stream>>>(isw, idn, bukBase, counts, rowStart, csr_pair);

    if (schemeA) {
        unsigned short* m27 = (unsigned short*)big;
        float* m1 = out;  // slice 0

        (void)hipMemsetAsync(col_of_node, 0xFF, (size_t)N_NODES * 4, stream);
        (void)hipMemsetAsync(flag, 0, (size_t)N_NODES * 4, stream);
        (void)hipMemsetAsync(m1, 0, NB * 4, stream);

        colmap_kernel<<<1, 256, 0, stream>>>(bi, col_of_node, next_dup);
        m1_edges_kernel<<<eb, 256, 0, stream>>>(src, dst, ew, col_of_node, next_dup,
                                                m1, flag, E);
        spmm_k2<<<nodeGrid, 256, 0, stream>>>(m1, m27, rowStart, counts, csr_pair, flag);
        for (int k = 3; k <= 7; ++k) {
            spmm_bf<<<nodeGrid, 256, 0, stream>>>(m27 + (size_t)(k - 3) * NB,
                                                  m27 + (size_t)(k - 2) * NB,
                                                  rowStart, counts, csr_pair);
        }
        spmm_bf_last<<<nodeGrid, 256, 0, stream>>>(m27, rowStart, counts, csr_pair,
                                                   coeffs, flag, out, bi);
    } else {
        float* fbig = (float*)big;
        float* mpow[ORDER + 1];
        for (int k = 1; k <= 4; ++k) mpow[k] = fbig + (size_t)(k - 1) * NB;
        for (int k = 5; k <= 8; ++k) mpow[k] = out + (size_t)(k - 5) * NB;

        (void)hipMemsetAsync(col_of_node, 0xFF, (size_t)N_NODES * 4, stream);
        (void)hipMemsetAsync(flag, 0, (size_t)N_NODES * 4, stream);
        (void)hipMemsetAsync(mpow[1], 0, NB * 4, stream);
        colmap_kernel<<<1, 256, 0, stream>>>(bi, col_of_node, next_dup);
        m1_edges_kernel<<<eb, 256, 0, stream>>>(src, dst, ew, col_of_node, next_dup,
                                                mpow[1], flag, E);
        for (int h = 0; h < 2; ++h) {
            int colOff = h * 128;
            for (int k = 2; k <= ORDER; ++k) {
                spmm_half<<<nodeGrid, 256, 0, stream>>>(mpow[k - 1], mpow[k],
                                                        rowStart, counts, csr_pair, colOff);
            }
        }
        combine_kernel<<<cgrid, 256, 0, stream>>>(out, fbig, coeffs, bi);
    }
}